// Round 8
// baseline (394.725 us; speedup 1.0000x reference)
//
#include <hip/hip_runtime.h>
#include <hip/hip_bf16.h>
#include <math.h>

// Sizes: B=16, N=64, nE=128, H=128, LAT=128, NS=64, NV=32, INV=96, D_NODE=160
#define SQRT3F 1.7320508075688772f
#define ALPHAF 0.10206207261596577f  // 1/sqrt(96)
#define PIF 3.14159265358979323846f

typedef short v8s __attribute__((ext_vector_type(8)));
typedef float v4f __attribute__((ext_vector_type(4)));

__device__ __forceinline__ float silu_f(float x) {
  return x / (1.0f + __expf(-x));
}
__device__ __forceinline__ float sigmoid_f(float x) {
  return 1.0f / (1.0f + __expf(-x));
}
__device__ __forceinline__ unsigned short f2bf(float f) {
  unsigned int u = __float_as_uint(f);
  unsigned int r = (u + 0x7fffu + ((u >> 16) & 1u)) >> 16;
  return (unsigned short)r;
}
__device__ __forceinline__ float bf2f(unsigned short h) {
  return __uint_as_float(((unsigned int)h) << 16);
}

// ---------------------------------------------------------------------------
// K-1 v2: cast W2 (128 x 9216 fp32) into MFMA B-FRAGMENT order, bf16 hi/lo:
// W2f[((T*4+ks)*64 + lane)*8 + j] = W2[ks*32+(lane>>4)*8+j][T*16+(lane&15)]
// so k_tp's B-loads are fully coalesced 1KB wave-loads. grid=576, block=256.
// ---------------------------------------------------------------------------
__global__ void __launch_bounds__(256) k_castw2(
    const float* __restrict__ W2, unsigned short* __restrict__ W2fh,
    unsigned short* __restrict__ W2fl) {
  const int T = blockIdx.x;           // column tile of 16
  const int tid = threadIdx.x;
  __shared__ float Tl[128][17];

  for (int idx = tid; idx < 2048; idx += 256) {
    int k = idx >> 4, cc = idx & 15;
    Tl[k][cc] = W2[(size_t)k * 9216 + T * 16 + cc];
  }
  __syncthreads();

  const int ks = tid >> 6, lane = tid & 63;
  const int q = lane >> 4, cq = lane & 15;
  const int k0 = ks * 32 + q * 8;
  unsigned short hv[8], lv[8];
  #pragma unroll
  for (int j = 0; j < 8; ++j) {
    float wv = Tl[k0 + j][cq];
    unsigned short h = f2bf(wv);
    hv[j] = h;
    lv[j] = f2bf(wv - bf2f(h));
  }
  size_t base = ((size_t)(T * 4 + ks) * 64 + lane) * 8;
  *(uint4*)&W2fh[base] = *(uint4*)hv;
  *(uint4*)&W2fl[base] = *(uint4*)lv;
}

// ---------------------------------------------------------------------------
// K-2: pack sc_W1 (128x128) into MFMA B-fragment order, bf16 hi/lo.
// ---------------------------------------------------------------------------
__global__ void __launch_bounds__(256) k_castw1(
    const float* __restrict__ W1, unsigned short* __restrict__ W1fh,
    unsigned short* __restrict__ W1fl) {
  const int s = blockIdx.x * 256 + threadIdx.x;   // 0..2047
  const int lane = s & 63;
  const int t = (s >> 6) & 7;
  const int ks = s >> 9;
  const int kbase = ks * 32 + (lane >> 4) * 8;
  const int n = t * 16 + (lane & 15);
  unsigned short hv[8], lv[8];
  #pragma unroll
  for (int j = 0; j < 8; ++j) {
    float w = W1[(size_t)(kbase + j) * 128 + n];
    unsigned short h = f2bf(w);
    hv[j] = h;
    lv[j] = f2bf(w - bf2f(h));
  }
  *(uint4*)&W1fh[(size_t)s * 8] = *(uint4*)hv;
  *(uint4*)&W1fl[(size_t)s * 8] = *(uint4*)lv;
}

// ---------------------------------------------------------------------------
// K0: per-node prep, 4 nodes per block. grid=256, block=128.
// Emits hidden as bf16 hi/lo, node-major [1024][128].
// ---------------------------------------------------------------------------
__global__ void k_prep(const float* __restrict__ hf, const int* __restrict__ z,
                       const float* __restrict__ pos, const float* __restrict__ z_emb,
                       const float* __restrict__ vwW0, const float* __restrict__ vwb0,
                       const float* __restrict__ vwW1, const float* __restrict__ vwb1,
                       const float* __restrict__ scW0,
                       unsigned short* __restrict__ hTh, unsigned short* __restrict__ hTl,
                       float* __restrict__ Pn, float* __restrict__ Pa,
                       float* __restrict__ xvu, float* __restrict__ y1cw) {
  const int g0 = blockIdx.x * 4;
  const int b = g0 >> 6;
  const int t = threadIdx.x;

  __shared__ float vin[4][64];
  __shared__ float invn[4][96];
  __shared__ float h0[4][128];
  __shared__ float uS[4][3];
  __shared__ float rS[4];

  if (t < 4) {
    const int g = g0 + t;
    float px = pos[g * 3 + 0] - pos[(b * 64) * 3 + 0];
    float py = pos[g * 3 + 1] - pos[(b * 64) * 3 + 1];
    float pz = pos[g * 3 + 2] - pos[(b * 64) * 3 + 2];
    float r = sqrtf(px * px + py * py + pz * pz + 1e-12f);
    float rm = fmaxf(r, 1e-8f);
    uS[t][0] = px / rm; uS[t][1] = py / rm; uS[t][2] = pz / rm;
    rS[t] = r;
  }
  __syncthreads();

  if (t < 32) {
    const float delta = 6.0f / 31.0f;
    const float gamma = 1.0f / (delta * delta + 1e-12f);
    #pragma unroll
    for (int nn = 0; nn < 4; ++nn) {
      int zi = z[g0 + nn];
      vin[nn][t] = z_emb[zi * 32 + t];
      float rc = fminf(rS[nn], 6.0f);
      float d = rc - (float)t * delta;
      vin[nn][32 + t] = __expf(-gamma * d * d);
      float a = hf[(g0 + nn) * 160 + 64 + t * 3 + 0] * uS[nn][0]
              + hf[(g0 + nn) * 160 + 64 + t * 3 + 1] * uS[nn][1]
              + hf[(g0 + nn) * 160 + 64 + t * 3 + 2] * uS[nn][2];
      xvu[(g0 + nn) * 32 + t] = a;
    }
  }
  if (t < 96) {
    #pragma unroll
    for (int nn = 0; nn < 4; ++nn) {
      const int g = g0 + nn;
      if (t < 64) {
        invn[nn][t] = hf[g * 160 + t];
      } else {
        int o = t - 64;
        float v0 = hf[g * 160 + 64 + o * 3 + 0];
        float v1 = hf[g * 160 + 64 + o * 3 + 1];
        float v2 = hf[g * 160 + 64 + o * 3 + 2];
        invn[nn][t] = sqrtf((v0 * v0 + v1 * v1 + v2 * v2) * (1.0f / 3.0f) + 1e-8f);
      }
    }
  }
  if (t < 4) {
    const int n = (g0 + t) & 63;
    float r = rS[t];
    float cw = 0.0f;
    if (r <= 6.0f && n != 0) cw = 0.5f * (cosf(PIF * r * (1.0f / 6.0f)) + 1.0f);
    y1cw[(g0 + t) * 4 + 0] = SQRT3F * uS[t][0];
    y1cw[(g0 + t) * 4 + 1] = SQRT3F * uS[t][1];
    y1cw[(g0 + t) * 4 + 2] = SQRT3F * uS[t][2];
    y1cw[(g0 + t) * 4 + 3] = cw;
  }
  __syncthreads();

  {
    float a0 = vwb0[t], a1 = a0, a2 = a0, a3 = a0;
    #pragma unroll 8
    for (int k = 0; k < 64; ++k) {
      float w = vwW0[k * 128 + t];
      a0 = fmaf(vin[0][k], w, a0);
      a1 = fmaf(vin[1][k], w, a1);
      a2 = fmaf(vin[2][k], w, a2);
      a3 = fmaf(vin[3][k], w, a3);
    }
    h0[0][t] = silu_f(a0); h0[1][t] = silu_f(a1);
    h0[2][t] = silu_f(a2); h0[3][t] = silu_f(a3);
  }
  __syncthreads();
  {
    float a0 = vwb1[t], a1 = a0, a2 = a0, a3 = a0;
    #pragma unroll 8
    for (int k = 0; k < 128; ++k) {
      float w = vwW1[k * 128 + t];
      a0 = fmaf(h0[0][k], w, a0);
      a1 = fmaf(h0[1][k], w, a1);
      a2 = fmaf(h0[2][k], w, a2);
      a3 = fmaf(h0[3][k], w, a3);
    }
    float hv[4] = {silu_f(a0), silu_f(a1), silu_f(a2), silu_f(a3)};
    #pragma unroll
    for (int nn = 0; nn < 4; ++nn) {
      unsigned short hh = f2bf(hv[nn]);
      hTh[(size_t)(g0 + nn) * 128 + t] = hh;
      hTl[(size_t)(g0 + nn) * 128 + t] = f2bf(hv[nn] - bf2f(hh));
    }
  }
  {
    float p0 = 0.f, p1 = 0.f, p2 = 0.f, p3 = 0.f;
    #pragma unroll 8
    for (int k = 0; k < 96; ++k) {
      float w = scW0[(96 + k) * 128 + t];
      p0 = fmaf(invn[0][k], w, p0);
      p1 = fmaf(invn[1][k], w, p1);
      p2 = fmaf(invn[2][k], w, p2);
      p3 = fmaf(invn[3][k], w, p3);
    }
    #pragma unroll 8
    for (int k = 0; k < 64; ++k) {
      float w = scW0[(192 + k) * 128 + t];
      p0 = fmaf(vin[0][k], w, p0);
      p1 = fmaf(vin[1][k], w, p1);
      p2 = fmaf(vin[2][k], w, p2);
      p3 = fmaf(vin[3][k], w, p3);
    }
    Pn[(g0 + 0) * 128 + t] = p0;
    Pn[(g0 + 1) * 128 + t] = p1;
    Pn[(g0 + 2) * 128 + t] = p2;
    Pn[(g0 + 3) * 128 + t] = p3;
  }
  if ((g0 & 63) == 0) {
    float p = 0.0f;
    #pragma unroll 8
    for (int k = 0; k < 96; ++k) p = fmaf(invn[0][k], scW0[k * 128 + t], p);
    Pa[b * 128 + t] = p;
  }
}

// ---------------------------------------------------------------------------
// KPe: Pe[e][t] = sc_b0[t] + e_feat[e]@We. grid=128, block=128.
// ---------------------------------------------------------------------------
__global__ void k_pe(const float* __restrict__ e_feat, const float* __restrict__ scW0,
                     const float* __restrict__ scb0, float* __restrict__ Pe) {
  const int e = blockIdx.x;
  const int t = threadIdx.x;
  float a = scb0[t];
  #pragma unroll
  for (int k = 0; k < 16; ++k) a = fmaf(e_feat[e * 16 + k], scW0[(256 + k) * 128 + t], a);
  Pe[e * 128 + t] = a;
}

// ---------------------------------------------------------------------------
// K2 v8: MFMA GEMM + contraction, REGISTER-accumulated.
// grid = (64 node-tiles of 16, 2 col-halves), block = 256 (4 waves).
// Each wave owns contiguous per-segment tile ranges so the contraction
// output slot is a compile-time loop index -> register accumulators.
// One LDS combine + one small global-atomic flush (2-way collisions).
// R7 lesson: cross-XCD global atomics at 576-blocks scale ping-ponged 90MB
// through HBM — this version's flush is ~1.3MB total.
// ---------------------------------------------------------------------------
__global__ void __launch_bounds__(256) k_tp(
    const unsigned short* __restrict__ hTh, const unsigned short* __restrict__ hTl,
    const unsigned short* __restrict__ W2fh, const unsigned short* __restrict__ W2fl,
    const float* __restrict__ b2, const float* __restrict__ hf,
    const float* __restrict__ xvu, const float* __restrict__ y1cw,
    float* __restrict__ values) {
  const int g0 = blockIdx.x * 16;
  const int ch = blockIdx.y;          // column half 0/1
  const int tid = threadIdx.x;
  const int w = tid >> 6, l = tid & 63;
  const int q = l >> 4, cq = l & 15;

  __shared__ float xsS[16][64];
  __shared__ float xvS[16][96];
  __shared__ float xvuS[16][32];
  __shared__ float y1S[16][4];
  __shared__ float valsS[16][160];
  __shared__ float svS[16][32];

  for (int idx = tid; idx < 16 * 64; idx += 256) {
    int n = idx >> 6, i = idx & 63;
    xsS[n][i] = hf[(size_t)(g0 + n) * 160 + i];
  }
  for (int idx = tid; idx < 16 * 96; idx += 256) {
    int n = idx / 96, k = idx - n * 96;
    xvS[n][k] = hf[(size_t)(g0 + n) * 160 + 64 + k];
  }
  for (int idx = tid; idx < 16 * 32; idx += 256) {
    int n = idx >> 5, i = idx & 31;
    xvuS[n][i] = xvu[(size_t)(g0 + n) * 32 + i];
  }
  if (tid < 64) ((float*)y1S)[tid] = y1cw[(size_t)g0 * 4 + tid];
  for (int idx = tid; idx < 16 * 160; idx += 256) ((float*)valsS)[idx] = 0.f;
  for (int idx = tid; idx < 16 * 32; idx += 256) ((float*)svS)[idx] = 0.f;

  // A fragments: all waves share the block's 16 nodes (m=cq, k=q*8+j).
  v8s ah[4], al[4];
  #pragma unroll
  for (int ks = 0; ks < 4; ++ks) {
    ah[ks] = *(const v8s*)&hTh[(size_t)(g0 + cq) * 128 + ks * 32 + q * 8];
    al[ks] = *(const v8s*)&hTl[(size_t)(g0 + cq) * 128 + ks * 32 + q * 8];
  }
  __syncthreads();

  // per-tile: 8 coalesced v8s B-loads, 12 MFMAs, bias add -> tp per D-row.
  auto tile_tp = [&](int T) -> v4f {
    v4f a = (v4f){0.f, 0.f, 0.f, 0.f};
    const unsigned short* ph = W2fh + ((size_t)T * 4 * 64) * 8;
    const unsigned short* pl = W2fl + ((size_t)T * 4 * 64) * 8;
    #pragma unroll
    for (int ks = 0; ks < 4; ++ks) {
      v8s bh = *(const v8s*)(ph + (size_t)(ks * 64 + l) * 8);
      v8s bl = *(const v8s*)(pl + (size_t)(ks * 64 + l) * 8);
      a = __builtin_amdgcn_mfma_f32_16x16x32_bf16(ah[ks], bh, a, 0, 0, 0);
      a = __builtin_amdgcn_mfma_f32_16x16x32_bf16(al[ks], bh, a, 0, 0, 0);
      a = __builtin_amdgcn_mfma_f32_16x16x32_bf16(ah[ks], bl, a, 0, 0, 0);
    }
    float bj = b2[T * 16 + cq];
    a[0] += bj; a[1] += bj; a[2] += bj; a[3] += bj;
    return a;
  };

  // ---- w1 segment: T in [ch*128 + w*32, +32), i = T>>2, o = (T&3)*16+cq ----
  {
    const int T0 = ch * 128 + w * 32;
    const int i0 = T0 >> 2;
    float racc[4][4] = {{0.f}};
    for (int ii = 0; ii < 8; ++ii) {
      #pragma unroll
      for (int m = 0; m < 4; ++m) {
        v4f tp = tile_tp(T0 + ii * 4 + m);
        #pragma unroll
        for (int r = 0; r < 4; ++r)
          racc[m][r] = fmaf(xsS[q * 4 + r][i0 + ii], tp[r], racc[m][r]);
      }
    }
    #pragma unroll
    for (int m = 0; m < 4; ++m)
      #pragma unroll
      for (int r = 0; r < 4; ++r)
        atomicAdd(&valsS[q * 4 + r][m * 16 + cq], racc[m][r]);
  }

  // ---- w2 segment: T in [256 + ch*64 + w*16, +16), i=(T-256)>>1, o=(T&1)*16+cq
  {
    const int T0 = 256 + ch * 64 + w * 16;
    const int i0 = (T0 - 256) >> 1;
    float racc[2][4] = {{0.f}};
    for (int ii = 0; ii < 8; ++ii) {
      #pragma unroll
      for (int m = 0; m < 2; ++m) {
        v4f tp = tile_tp(T0 + ii * 2 + m);
        #pragma unroll
        for (int r = 0; r < 4; ++r)
          racc[m][r] = fmaf(xsS[q * 4 + r][i0 + ii], tp[r], racc[m][r]);
      }
    }
    #pragma unroll
    for (int m = 0; m < 2; ++m)
      #pragma unroll
      for (int r = 0; r < 4; ++r)
        atomicAdd(&svS[q * 4 + r][m * 16 + cq], racc[m][r]);
  }

  // ---- w3 segment: T in [384 + ch*32 + w*8, +8), i=(T-384)>>1, o=(T&1)*16+cq
  {
    const int T0 = 384 + ch * 32 + w * 8;
    const int i0 = (T0 - 384) >> 1;
    float racc[2][4][3] = {{{0.f}}};
    for (int ii = 0; ii < 4; ++ii) {
      #pragma unroll
      for (int m = 0; m < 2; ++m) {
        v4f tp = tile_tp(T0 + ii * 2 + m);
        #pragma unroll
        for (int r = 0; r < 4; ++r)
          #pragma unroll
          for (int cc = 0; cc < 3; ++cc)
            racc[m][r][cc] = fmaf(xvS[q * 4 + r][3 * (i0 + ii) + cc], tp[r],
                                  racc[m][r][cc]);
      }
    }
    #pragma unroll
    for (int m = 0; m < 2; ++m)
      #pragma unroll
      for (int r = 0; r < 4; ++r)
        #pragma unroll
        for (int cc = 0; cc < 3; ++cc)
          atomicAdd(&valsS[q * 4 + r][64 + 3 * (m * 16 + cq) + cc], racc[m][r][cc]);
  }

  // ---- w4 segment: T in [448 + ch*64 + w*16, +16), i=(T-448)>>2, o=(T&3)*16+cq
  {
    const int T0 = 448 + ch * 64 + w * 16;
    const int i0 = (T0 - 448) >> 2;
    float racc[4][4] = {{0.f}};
    for (int ii = 0; ii < 4; ++ii) {
      #pragma unroll
      for (int m = 0; m < 4; ++m) {
        v4f tp = tile_tp(T0 + ii * 4 + m);
        #pragma unroll
        for (int r = 0; r < 4; ++r)
          racc[m][r] = fmaf(xvuS[q * 4 + r][i0 + ii], tp[r], racc[m][r]);
      }
    }
    #pragma unroll
    for (int m = 0; m < 4; ++m)
      #pragma unroll
      for (int r = 0; r < 4; ++r)
        atomicAdd(&valsS[q * 4 + r][m * 16 + cq], racc[m][r]);
  }
  __syncthreads();

  // flush: combine sv*y1 into vector part, one atomicAdd per element
  // (2 col-half blocks collide per element; values pre-zeroed by memset).
  for (int idx = tid; idx < 2560; idx += 256) {
    int n = idx / 160, d = idx - n * 160;
    float v = valsS[n][d];
    if (d >= 64) {
      int dd = d - 64, o = dd / 3, cc = dd - 3 * o;
      v = fmaf(svS[n][o], y1S[n][cc], v);
    }
    atomicAdd(&values[(size_t)(g0 + n) * 160 + d], ALPHAF * v);
  }
}

// ---------------------------------------------------------------------------
// K3 v4: MFMA gate MLP + aggregation per (b,e). grid=2048, block=256.
// (unchanged from R7)
// ---------------------------------------------------------------------------
__global__ void __launch_bounds__(256, 4) k_gate_agg(
    const float* __restrict__ Pa, const float* __restrict__ Pe,
    const float* __restrict__ Pn,
    const unsigned short* __restrict__ W1fh, const unsigned short* __restrict__ W1fl,
    const float* __restrict__ b1, const float* __restrict__ W2v,
    const float* __restrict__ b2s, const float* __restrict__ y1cw,
    const float* __restrict__ values, float* __restrict__ inv_agg) {
  const int bid = blockIdx.x;
  const int b = bid >> 7, e = bid & 127;
  const int tid = threadIdx.x;

  __shared__ float Prow[128];
  __shared__ float gpre[64];
  __shared__ float gateL[64];
  __shared__ float aggL[160];
  __shared__ float normS;

  if (tid < 128) Prow[tid] = Pa[b * 128 + tid] + Pe[e * 128 + tid];
  __syncthreads();

  const int w = tid >> 6, l = tid & 63;
  const int q = l >> 4, cq = l & 15;
  const int node = w * 16 + cq;
  const float* pnrow = Pn + (size_t)(b * 64 + node) * 128;

  v4f acc[8];
  #pragma unroll
  for (int t = 0; t < 8; ++t) acc[t] = (v4f){0.f, 0.f, 0.f, 0.f};

  #pragma unroll
  for (int ks = 0; ks < 4; ++ks) {
    const int k0 = ks * 32 + q * 8;
    float4 p0 = *(const float4*)(pnrow + k0);
    float4 p1 = *(const float4*)(pnrow + k0 + 4);
    float4 r0 = *(const float4*)(&Prow[k0]);
    float4 r1 = *(const float4*)(&Prow[k0 + 4]);
    float xv[8] = {p0.x + r0.x, p0.y + r0.y, p0.z + r0.z, p0.w + r0.w,
                   p1.x + r1.x, p1.y + r1.y, p1.z + r1.z, p1.w + r1.w};
    v8s avh, avl;
    #pragma unroll
    for (int j = 0; j < 8; ++j) {
      float x = silu_f(xv[j]);
      unsigned short h = f2bf(x);
      avh[j] = (short)h;
      avl[j] = (short)f2bf(x - bf2f(h));
    }
    #pragma unroll
    for (int t = 0; t < 8; ++t) {
      const size_t fb = (size_t)((ks * 8 + t) * 64 + l) * 8;
      v8s bh = *(const v8s*)&W1fh[fb];
      v8s bl = *(const v8s*)&W1fl[fb];
      acc[t] = __builtin_amdgcn_mfma_f32_16x16x32_bf16(avh, bh, acc[t], 0, 0, 0);
      acc[t] = __builtin_amdgcn_mfma_f32_16x16x32_bf16(avl, bh, acc[t], 0, 0, 0);
      acc[t] = __builtin_amdgcn_mfma_f32_16x16x32_bf16(avh, bl, acc[t], 0, 0, 0);
    }
  }

  float part0 = 0.f, part1 = 0.f, part2 = 0.f, part3 = 0.f;
  #pragma unroll
  for (int t = 0; t < 8; ++t) {
    float bb = b1[t * 16 + cq];
    float wg = W2v[t * 16 + cq];
    part0 = fmaf(silu_f(acc[t][0] + bb), wg, part0);
    part1 = fmaf(silu_f(acc[t][1] + bb), wg, part1);
    part2 = fmaf(silu_f(acc[t][2] + bb), wg, part2);
    part3 = fmaf(silu_f(acc[t][3] + bb), wg, part3);
  }
  #pragma unroll
  for (int off = 1; off < 16; off <<= 1) {
    part0 += __shfl_xor(part0, off);
    part1 += __shfl_xor(part1, off);
    part2 += __shfl_xor(part2, off);
    part3 += __shfl_xor(part3, off);
  }
  if (cq == 0) {
    gpre[w * 16 + q * 4 + 0] = part0;
    gpre[w * 16 + q * 4 + 1] = part1;
    gpre[w * 16 + q * 4 + 2] = part2;
    gpre[w * 16 + q * 4 + 3] = part3;
  }
  __syncthreads();

  if (tid < 64) {
    float gv = sigmoid_f(gpre[tid] + b2s[0]);
    gv *= y1cw[(b * 64 + tid) * 4 + 3];
    gateL[tid] = gv;
    float t2 = gv;
    #pragma unroll
    for (int off = 32; off > 0; off >>= 1) t2 += __shfl_down(t2, off);
    if (tid == 0) normS = fmaxf(t2, 1e-8f);
  }
  __syncthreads();

  if (tid < 160) {
    float a = 0.0f;
    const float* vp = values + (size_t)b * 64 * 160 + tid;
    #pragma unroll 4
    for (int n = 0; n < 64; ++n) a = fmaf(gateL[n], vp[n * 160], a);
    aggL[tid] = a / normS;
  }
  __syncthreads();
  if (tid < 96) {
    float rv;
    if (tid < 64) {
      rv = aggL[tid];
    } else {
      int o = tid - 64;
      float a0 = aggL[64 + o * 3 + 0];
      float a1 = aggL[64 + o * 3 + 1];
      float a2 = aggL[64 + o * 3 + 2];
      rv = sqrtf((a0 * a0 + a1 * a1 + a2 * a2) * (1.0f / 3.0f) + 1e-8f);
    }
    inv_agg[bid * 96 + tid] = rv;
  }
}

// ---------------------------------------------------------------------------
// K4: MLP layer Y = act(X@W + b). 32-row tiles -> 64 blocks. K in {96,128}.
// ---------------------------------------------------------------------------
__global__ void __launch_bounds__(256) k_mlp(
    const float* __restrict__ X, const float* __restrict__ W,
    const float* __restrict__ bias, float* __restrict__ Y,
    int K, int act) {
  const int r0 = blockIdx.x * 32;
  const int tid = threadIdx.x;

  __shared__ float A[32][129];

  for (int idx = tid; idx < 32 * K; idx += 256) {
    int n = idx / K, k = idx - n * K;
    A[n][k] = X[(size_t)(r0 + n) * K + k];
  }
  __syncthreads();

  const int rowg = tid >> 4, colg = tid & 15;
  const int r2 = rowg * 2, c8 = colg * 8;

  float acc[2][8];
  #pragma unroll
  for (int i = 0; i < 2; ++i)
    #pragma unroll
    for (int jj = 0; jj < 8; ++jj) acc[i][jj] = 0.0f;

  const float* wptr = W + c8;
  #pragma unroll 4
  for (int k = 0; k < K; ++k) {
    float4 w0 = *(const float4*)(wptr + k * 128);
    float4 w1v = *(const float4*)(wptr + k * 128 + 4);
    float av0 = A[r2 + 0][k];
    float av1 = A[r2 + 1][k];
    float wv[8] = {w0.x, w0.y, w0.z, w0.w, w1v.x, w1v.y, w1v.z, w1v.w};
    #pragma unroll
    for (int jj = 0; jj < 8; ++jj) {
      acc[0][jj] = fmaf(av0, wv[jj], acc[0][jj]);
      acc[1][jj] = fmaf(av1, wv[jj], acc[1][jj]);
    }
  }

  #pragma unroll
  for (int jj = 0; jj < 8; ++jj) {
    float bb = bias[c8 + jj];
    #pragma unroll
    for (int i = 0; i < 2; ++i) {
      float v = acc[i][jj] + bb;
      if (act) v = silu_f(v);
      Y[(size_t)(r0 + r2 + i) * 128 + c8 + jj] = v;
    }
  }
}

// ---------------------------------------------------------------------------
extern "C" void kernel_launch(void* const* d_in, const int* in_sizes, int n_in,
                              void* d_out, int out_size, void* d_ws, size_t ws_size,
                              hipStream_t stream) {
  const float* hf    = (const float*)d_in[0];
  const int*   z     = (const int*)  d_in[1];
  const float* pos   = (const float*)d_in[2];
  const float* e_feat= (const float*)d_in[4];
  const float* z_emb = (const float*)d_in[5];
  const float* vwW0  = (const float*)d_in[6];
  const float* vwb0  = (const float*)d_in[7];
  const float* vwW1  = (const float*)d_in[8];
  const float* vwb1  = (const float*)d_in[9];
  const float* vwW2  = (const float*)d_in[10];
  const float* vwb2  = (const float*)d_in[11];
  const float* scW0  = (const float*)d_in[12];
  const float* scb0  = (const float*)d_in[13];
  const float* scW1  = (const float*)d_in[14];
  const float* scb1  = (const float*)d_in[15];
  const float* scW2  = (const float*)d_in[16];
  const float* scb2  = (const float*)d_in[17];
  const float* oW0   = (const float*)d_in[18];
  const float* ob0   = (const float*)d_in[19];
  const float* oW1   = (const float*)d_in[20];
  const float* ob1   = (const float*)d_in[21];
  const float* oW2   = (const float*)d_in[22];
  const float* ob2   = (const float*)d_in[23];
  float* out = (float*)d_out;

  float* ws = (float*)d_ws;
  unsigned short* W2fh = (unsigned short*)(ws);            // 589824 fl
  unsigned short* W2fl = (unsigned short*)(ws + 589824);   // 589824 fl
  unsigned short* hTh  = (unsigned short*)(ws + 1179648);  // 65536 fl
  unsigned short* hTl  = (unsigned short*)(ws + 1245184);  // 65536 fl
  float* Pn     = ws + 1310720;   // 131072
  float* Pa     = Pn + 131072;    // 2048
  float* Pe     = Pa + 2048;      // 16384
  float* xvu    = Pe + 16384;     // 32768
  float* y1cw   = xvu + 32768;    // 4096
  float* values = y1cw + 4096;    // 163840
  float* invagg = values + 163840;// 196608
  unsigned short* W1fh = (unsigned short*)(invagg + 196608);  // 8192 fl
  unsigned short* W1fl = (unsigned short*)(invagg + 196608 + 8192);
  // H1/H2 alias the W2f region (dead after k_tp)
  float* H1     = ws;             // 262144
  float* H2     = ws + 262144;    // 262144

  hipMemsetAsync(values, 0, 163840 * sizeof(float), stream);

  k_castw2<<<576, 256, 0, stream>>>(vwW2, W2fh, W2fl);
  k_castw1<<<8, 256, 0, stream>>>(scW1, W1fh, W1fl);
  k_prep<<<256, 128, 0, stream>>>(hf, z, pos, z_emb, vwW0, vwb0, vwW1, vwb1,
                                  scW0, hTh, hTl, Pn, Pa, xvu, y1cw);
  k_pe<<<128, 128, 0, stream>>>(e_feat, scW0, scb0, Pe);
  k_tp<<<dim3(64, 2), 256, 0, stream>>>(hTh, hTl, W2fh, W2fl, vwb2, hf, xvu,
                                        y1cw, values);
  k_gate_agg<<<2048, 256, 0, stream>>>(Pa, Pe, Pn, W1fh, W1fl, scb1, scW2, scb2,
                                       y1cw, values, invagg);
  k_mlp<<<64, 256, 0, stream>>>(invagg, oW0, ob0, H1, 96, 1);
  k_mlp<<<64, 256, 0, stream>>>(H1, oW1, ob1, H2, 128, 1);
  k_mlp<<<64, 256, 0, stream>>>(H2, oW2, ob2, out, 128, 0);
}

// Round 9
// 335.563 us; speedup vs baseline: 1.1763x; 1.1763x over previous
//
#include <hip/hip_runtime.h>
#include <hip/hip_bf16.h>
#include <math.h>

// Sizes: B=16, N=64, nE=128, H=128, LAT=128, NS=64, NV=32, INV=96, D_NODE=160
#define SQRT3F 1.7320508075688772f
#define ALPHAF 0.10206207261596577f  // 1/sqrt(96)
#define PIF 3.14159265358979323846f

typedef short v8s __attribute__((ext_vector_type(8)));
typedef float v4f __attribute__((ext_vector_type(4)));

__device__ __forceinline__ float silu_f(float x) {
  return x / (1.0f + __expf(-x));
}
__device__ __forceinline__ float sigmoid_f(float x) {
  return 1.0f / (1.0f + __expf(-x));
}
__device__ __forceinline__ unsigned short f2bf(float f) {
  unsigned int u = __float_as_uint(f);
  unsigned int r = (u + 0x7fffu + ((u >> 16) & 1u)) >> 16;
  return (unsigned short)r;
}
__device__ __forceinline__ float bf2f(unsigned short h) {
  return __uint_as_float(((unsigned int)h) << 16);
}

// ---------------------------------------------------------------------------
// K-1 v2: cast W2 (128 x 9216 fp32) into MFMA B-FRAGMENT order, bf16 hi/lo:
// W2f[((T*4+ks)*64 + lane)*8 + j] = W2[ks*32+(lane>>4)*8+j][T*16+(lane&15)]
// ---------------------------------------------------------------------------
__global__ void __launch_bounds__(256) k_castw2(
    const float* __restrict__ W2, unsigned short* __restrict__ W2fh,
    unsigned short* __restrict__ W2fl) {
  const int T = blockIdx.x;           // column tile of 16
  const int tid = threadIdx.x;
  __shared__ float Tl[128][17];

  for (int idx = tid; idx < 2048; idx += 256) {
    int k = idx >> 4, cc = idx & 15;
    Tl[k][cc] = W2[(size_t)k * 9216 + T * 16 + cc];
  }
  __syncthreads();

  const int ks = tid >> 6, lane = tid & 63;
  const int q = lane >> 4, cq = lane & 15;
  const int k0 = ks * 32 + q * 8;
  unsigned short hv[8], lv[8];
  #pragma unroll
  for (int j = 0; j < 8; ++j) {
    float wv = Tl[k0 + j][cq];
    unsigned short h = f2bf(wv);
    hv[j] = h;
    lv[j] = f2bf(wv - bf2f(h));
  }
  size_t base = ((size_t)(T * 4 + ks) * 64 + lane) * 8;
  *(uint4*)&W2fh[base] = *(uint4*)hv;
  *(uint4*)&W2fl[base] = *(uint4*)lv;
}

// ---------------------------------------------------------------------------
// K-2: pack sc_W1 (128x128) into MFMA B-fragment order, bf16 hi/lo.
// ---------------------------------------------------------------------------
__global__ void __launch_bounds__(256) k_castw1(
    const float* __restrict__ W1, unsigned short* __restrict__ W1fh,
    unsigned short* __restrict__ W1fl) {
  const int s = blockIdx.x * 256 + threadIdx.x;   // 0..2047
  const int lane = s & 63;
  const int t = (s >> 6) & 7;
  const int ks = s >> 9;
  const int kbase = ks * 32 + (lane >> 4) * 8;
  const int n = t * 16 + (lane & 15);
  unsigned short hv[8], lv[8];
  #pragma unroll
  for (int j = 0; j < 8; ++j) {
    float w = W1[(size_t)(kbase + j) * 128 + n];
    unsigned short h = f2bf(w);
    hv[j] = h;
    lv[j] = f2bf(w - bf2f(h));
  }
  *(uint4*)&W1fh[(size_t)s * 8] = *(uint4*)hv;
  *(uint4*)&W1fl[(size_t)s * 8] = *(uint4*)lv;
}

// ---------------------------------------------------------------------------
// K0: per-node prep, 4 nodes per block. grid=256, block=128.
// ---------------------------------------------------------------------------
__global__ void k_prep(const float* __restrict__ hf, const int* __restrict__ z,
                       const float* __restrict__ pos, const float* __restrict__ z_emb,
                       const float* __restrict__ vwW0, const float* __restrict__ vwb0,
                       const float* __restrict__ vwW1, const float* __restrict__ vwb1,
                       const float* __restrict__ scW0,
                       unsigned short* __restrict__ hTh, unsigned short* __restrict__ hTl,
                       float* __restrict__ Pn, float* __restrict__ Pa,
                       float* __restrict__ xvu, float* __restrict__ y1cw) {
  const int g0 = blockIdx.x * 4;
  const int b = g0 >> 6;
  const int t = threadIdx.x;

  __shared__ float vin[4][64];
  __shared__ float invn[4][96];
  __shared__ float h0[4][128];
  __shared__ float uS[4][3];
  __shared__ float rS[4];

  if (t < 4) {
    const int g = g0 + t;
    float px = pos[g * 3 + 0] - pos[(b * 64) * 3 + 0];
    float py = pos[g * 3 + 1] - pos[(b * 64) * 3 + 1];
    float pz = pos[g * 3 + 2] - pos[(b * 64) * 3 + 2];
    float r = sqrtf(px * px + py * py + pz * pz + 1e-12f);
    float rm = fmaxf(r, 1e-8f);
    uS[t][0] = px / rm; uS[t][1] = py / rm; uS[t][2] = pz / rm;
    rS[t] = r;
  }
  __syncthreads();

  if (t < 32) {
    const float delta = 6.0f / 31.0f;
    const float gamma = 1.0f / (delta * delta + 1e-12f);
    #pragma unroll
    for (int nn = 0; nn < 4; ++nn) {
      int zi = z[g0 + nn];
      vin[nn][t] = z_emb[zi * 32 + t];
      float rc = fminf(rS[nn], 6.0f);
      float d = rc - (float)t * delta;
      vin[nn][32 + t] = __expf(-gamma * d * d);
      float a = hf[(g0 + nn) * 160 + 64 + t * 3 + 0] * uS[nn][0]
              + hf[(g0 + nn) * 160 + 64 + t * 3 + 1] * uS[nn][1]
              + hf[(g0 + nn) * 160 + 64 + t * 3 + 2] * uS[nn][2];
      xvu[(g0 + nn) * 32 + t] = a;
    }
  }
  if (t < 96) {
    #pragma unroll
    for (int nn = 0; nn < 4; ++nn) {
      const int g = g0 + nn;
      if (t < 64) {
        invn[nn][t] = hf[g * 160 + t];
      } else {
        int o = t - 64;
        float v0 = hf[g * 160 + 64 + o * 3 + 0];
        float v1 = hf[g * 160 + 64 + o * 3 + 1];
        float v2 = hf[g * 160 + 64 + o * 3 + 2];
        invn[nn][t] = sqrtf((v0 * v0 + v1 * v1 + v2 * v2) * (1.0f / 3.0f) + 1e-8f);
      }
    }
  }
  if (t < 4) {
    const int n = (g0 + t) & 63;
    float r = rS[t];
    float cw = 0.0f;
    if (r <= 6.0f && n != 0) cw = 0.5f * (cosf(PIF * r * (1.0f / 6.0f)) + 1.0f);
    y1cw[(g0 + t) * 4 + 0] = SQRT3F * uS[t][0];
    y1cw[(g0 + t) * 4 + 1] = SQRT3F * uS[t][1];
    y1cw[(g0 + t) * 4 + 2] = SQRT3F * uS[t][2];
    y1cw[(g0 + t) * 4 + 3] = cw;
  }
  __syncthreads();

  {
    float a0 = vwb0[t], a1 = a0, a2 = a0, a3 = a0;
    #pragma unroll 8
    for (int k = 0; k < 64; ++k) {
      float w = vwW0[k * 128 + t];
      a0 = fmaf(vin[0][k], w, a0);
      a1 = fmaf(vin[1][k], w, a1);
      a2 = fmaf(vin[2][k], w, a2);
      a3 = fmaf(vin[3][k], w, a3);
    }
    h0[0][t] = silu_f(a0); h0[1][t] = silu_f(a1);
    h0[2][t] = silu_f(a2); h0[3][t] = silu_f(a3);
  }
  __syncthreads();
  {
    float a0 = vwb1[t], a1 = a0, a2 = a0, a3 = a0;
    #pragma unroll 8
    for (int k = 0; k < 128; ++k) {
      float w = vwW1[k * 128 + t];
      a0 = fmaf(h0[0][k], w, a0);
      a1 = fmaf(h0[1][k], w, a1);
      a2 = fmaf(h0[2][k], w, a2);
      a3 = fmaf(h0[3][k], w, a3);
    }
    float hv[4] = {silu_f(a0), silu_f(a1), silu_f(a2), silu_f(a3)};
    #pragma unroll
    for (int nn = 0; nn < 4; ++nn) {
      unsigned short hh = f2bf(hv[nn]);
      hTh[(size_t)(g0 + nn) * 128 + t] = hh;
      hTl[(size_t)(g0 + nn) * 128 + t] = f2bf(hv[nn] - bf2f(hh));
    }
  }
  {
    float p0 = 0.f, p1 = 0.f, p2 = 0.f, p3 = 0.f;
    #pragma unroll 8
    for (int k = 0; k < 96; ++k) {
      float w = scW0[(96 + k) * 128 + t];
      p0 = fmaf(invn[0][k], w, p0);
      p1 = fmaf(invn[1][k], w, p1);
      p2 = fmaf(invn[2][k], w, p2);
      p3 = fmaf(invn[3][k], w, p3);
    }
    #pragma unroll 8
    for (int k = 0; k < 64; ++k) {
      float w = scW0[(192 + k) * 128 + t];
      p0 = fmaf(vin[0][k], w, p0);
      p1 = fmaf(vin[1][k], w, p1);
      p2 = fmaf(vin[2][k], w, p2);
      p3 = fmaf(vin[3][k], w, p3);
    }
    Pn[(g0 + 0) * 128 + t] = p0;
    Pn[(g0 + 1) * 128 + t] = p1;
    Pn[(g0 + 2) * 128 + t] = p2;
    Pn[(g0 + 3) * 128 + t] = p3;
  }
  if ((g0 & 63) == 0) {
    float p = 0.0f;
    #pragma unroll 8
    for (int k = 0; k < 96; ++k) p = fmaf(invn[0][k], scW0[k * 128 + t], p);
    Pa[b * 128 + t] = p;
  }
}

// ---------------------------------------------------------------------------
// KPe: Pe[e][t] = sc_b0[t] + e_feat[e]@We. grid=128, block=128.
// ---------------------------------------------------------------------------
__global__ void k_pe(const float* __restrict__ e_feat, const float* __restrict__ scW0,
                     const float* __restrict__ scb0, float* __restrict__ Pe) {
  const int e = blockIdx.x;
  const int t = threadIdx.x;
  float a = scb0[t];
  #pragma unroll
  for (int k = 0; k < 16; ++k) a = fmaf(e_feat[e * 16 + k], scW0[(256 + k) * 128 + t], a);
  Pe[e * 128 + t] = a;
}

// ---------------------------------------------------------------------------
// K2 v9: MFMA GEMM + register contraction, prefetched + 8-way column split.
// grid = (64 node-tiles of 16, 8 col-splits), block = 256 (4 waves).
// R8 lesson: 128 blocks = 0.5 waves/SIMD serialized ~576 L2-latency loads.
// Now 512 blocks (2 waves/SIMD) + explicit tile double-buffer (load tile t+1
// while MFMA-ing tile t). 18 tiles/wave. Flush = small global atomics
// (8-way; R8 measured 2-way at 1.3MB WRITE — scales to ~5MB, ~1us).
// ---------------------------------------------------------------------------
struct BF {
  v8s h0, h1, h2, h3, l0, l1, l2, l3;
  float bias;
};

__device__ __forceinline__ BF load_bf(const unsigned short* __restrict__ W2fh,
                                      const unsigned short* __restrict__ W2fl,
                                      const float* __restrict__ b2,
                                      int T, int l, int cq) {
  BF f;
  const size_t base = (size_t)T * 2048 + (size_t)l * 8;
  f.h0 = *(const v8s*)(W2fh + base);
  f.h1 = *(const v8s*)(W2fh + base + 512);
  f.h2 = *(const v8s*)(W2fh + base + 1024);
  f.h3 = *(const v8s*)(W2fh + base + 1536);
  f.l0 = *(const v8s*)(W2fl + base);
  f.l1 = *(const v8s*)(W2fl + base + 512);
  f.l2 = *(const v8s*)(W2fl + base + 1024);
  f.l3 = *(const v8s*)(W2fl + base + 1536);
  f.bias = b2[T * 16 + cq];
  return f;
}

__global__ void __launch_bounds__(256) k_tp(
    const unsigned short* __restrict__ hTh, const unsigned short* __restrict__ hTl,
    const unsigned short* __restrict__ W2fh, const unsigned short* __restrict__ W2fl,
    const float* __restrict__ b2, const float* __restrict__ hf,
    const float* __restrict__ xvu, const float* __restrict__ y1cw,
    float* __restrict__ values) {
  const int g0 = blockIdx.x * 16;
  const int ch = blockIdx.y;          // col split 0..7
  const int tid = threadIdx.x;
  const int w = tid >> 6, l = tid & 63;
  const int q = l >> 4, cq = l & 15;

  __shared__ float xsS[16][64];
  __shared__ float xvS[16][96];
  __shared__ float xvuS[16][32];
  __shared__ float y1S[16][4];
  __shared__ float valsS[16][160];
  __shared__ float svS[16][32];

  for (int idx = tid; idx < 16 * 64; idx += 256) {
    int n = idx >> 6, i = idx & 63;
    xsS[n][i] = hf[(size_t)(g0 + n) * 160 + i];
  }
  for (int idx = tid; idx < 16 * 96; idx += 256) {
    int n = idx / 96, k = idx - n * 96;
    xvS[n][k] = hf[(size_t)(g0 + n) * 160 + 64 + k];
  }
  for (int idx = tid; idx < 16 * 32; idx += 256) {
    int n = idx >> 5, i = idx & 31;
    xvuS[n][i] = xvu[(size_t)(g0 + n) * 32 + i];
  }
  if (tid < 64) ((float*)y1S)[tid] = y1cw[(size_t)g0 * 4 + tid];
  for (int idx = tid; idx < 16 * 160; idx += 256) ((float*)valsS)[idx] = 0.f;
  for (int idx = tid; idx < 16 * 32; idx += 256) ((float*)svS)[idx] = 0.f;

  // A fragments: block's 16 nodes (m=cq, k=q*8+j), shared by all waves.
  v8s ah0 = *(const v8s*)&hTh[(size_t)(g0 + cq) * 128 + 0 * 32 + q * 8];
  v8s ah1 = *(const v8s*)&hTh[(size_t)(g0 + cq) * 128 + 1 * 32 + q * 8];
  v8s ah2 = *(const v8s*)&hTh[(size_t)(g0 + cq) * 128 + 2 * 32 + q * 8];
  v8s ah3 = *(const v8s*)&hTh[(size_t)(g0 + cq) * 128 + 3 * 32 + q * 8];
  v8s al0 = *(const v8s*)&hTl[(size_t)(g0 + cq) * 128 + 0 * 32 + q * 8];
  v8s al1 = *(const v8s*)&hTl[(size_t)(g0 + cq) * 128 + 1 * 32 + q * 8];
  v8s al2 = *(const v8s*)&hTl[(size_t)(g0 + cq) * 128 + 2 * 32 + q * 8];
  v8s al3 = *(const v8s*)&hTl[(size_t)(g0 + cq) * 128 + 3 * 32 + q * 8];
  __syncthreads();

  #define TILE_MFMA(f, outp)                                                  \
    {                                                                         \
      v4f a_ = (v4f){0.f, 0.f, 0.f, 0.f};                                     \
      a_ = __builtin_amdgcn_mfma_f32_16x16x32_bf16(ah0, (f).h0, a_, 0, 0, 0); \
      a_ = __builtin_amdgcn_mfma_f32_16x16x32_bf16(al0, (f).h0, a_, 0, 0, 0); \
      a_ = __builtin_amdgcn_mfma_f32_16x16x32_bf16(ah0, (f).l0, a_, 0, 0, 0); \
      a_ = __builtin_amdgcn_mfma_f32_16x16x32_bf16(ah1, (f).h1, a_, 0, 0, 0); \
      a_ = __builtin_amdgcn_mfma_f32_16x16x32_bf16(al1, (f).h1, a_, 0, 0, 0); \
      a_ = __builtin_amdgcn_mfma_f32_16x16x32_bf16(ah1, (f).l1, a_, 0, 0, 0); \
      a_ = __builtin_amdgcn_mfma_f32_16x16x32_bf16(ah2, (f).h2, a_, 0, 0, 0); \
      a_ = __builtin_amdgcn_mfma_f32_16x16x32_bf16(al2, (f).h2, a_, 0, 0, 0); \
      a_ = __builtin_amdgcn_mfma_f32_16x16x32_bf16(ah2, (f).l2, a_, 0, 0, 0); \
      a_ = __builtin_amdgcn_mfma_f32_16x16x32_bf16(ah3, (f).h3, a_, 0, 0, 0); \
      a_ = __builtin_amdgcn_mfma_f32_16x16x32_bf16(al3, (f).h3, a_, 0, 0, 0); \
      a_ = __builtin_amdgcn_mfma_f32_16x16x32_bf16(ah3, (f).l3, a_, 0, 0, 0); \
      a_[0] += (f).bias; a_[1] += (f).bias; a_[2] += (f).bias; a_[3] += (f).bias; \
      outp = a_;                                                              \
    }

  // ---- w1: 8 tiles/wave. T = ch*32 + w*8 + t; i=T>>2, o=(t&3)*16+cq ----
  {
    const int T0 = ch * 32 + w * 8;
    const int i0 = T0 >> 2;
    float racc[4][4] = {{0.f}};
    BF cur = load_bf(W2fh, W2fl, b2, T0, l, cq);
    #pragma unroll
    for (int t = 0; t < 8; ++t) {
      BF nxt;
      if (t < 7) nxt = load_bf(W2fh, W2fl, b2, T0 + t + 1, l, cq);
      v4f tp; TILE_MFMA(cur, tp);
      const int ii = t >> 2, m = t & 3;
      #pragma unroll
      for (int r = 0; r < 4; ++r)
        racc[m][r] = fmaf(xsS[q * 4 + r][i0 + ii], tp[r], racc[m][r]);
      cur = nxt;
    }
    #pragma unroll
    for (int m = 0; m < 4; ++m)
      #pragma unroll
      for (int r = 0; r < 4; ++r)
        atomicAdd(&valsS[q * 4 + r][m * 16 + cq], racc[m][r]);
  }

  // ---- w2: 4 tiles/wave. T = 256 + ch*16 + w*4 + t; i=(T-256)>>1, o=(t&1)*16+cq
  {
    const int T0 = 256 + ch * 16 + w * 4;
    const int i0 = (T0 - 256) >> 1;
    float racc[2][4] = {{0.f}};
    BF cur = load_bf(W2fh, W2fl, b2, T0, l, cq);
    #pragma unroll
    for (int t = 0; t < 4; ++t) {
      BF nxt;
      if (t < 3) nxt = load_bf(W2fh, W2fl, b2, T0 + t + 1, l, cq);
      v4f tp; TILE_MFMA(cur, tp);
      const int ii = t >> 1, m = t & 1;
      #pragma unroll
      for (int r = 0; r < 4; ++r)
        racc[m][r] = fmaf(xsS[q * 4 + r][i0 + ii], tp[r], racc[m][r]);
      cur = nxt;
    }
    #pragma unroll
    for (int m = 0; m < 2; ++m)
      #pragma unroll
      for (int r = 0; r < 4; ++r)
        atomicAdd(&svS[q * 4 + r][m * 16 + cq], racc[m][r]);
  }

  // ---- w3: 2 tiles/wave. T = 384 + ch*8 + w*2 + t; i=(T-384)>>1, o=(t&1)*16+cq
  {
    const int T0 = 384 + ch * 8 + w * 2;
    const int i0 = (T0 - 384) >> 1;
    float racc[2][4][3] = {{{0.f}}};
    BF cur = load_bf(W2fh, W2fl, b2, T0, l, cq);
    #pragma unroll
    for (int t = 0; t < 2; ++t) {
      BF nxt;
      if (t < 1) nxt = load_bf(W2fh, W2fl, b2, T0 + 1, l, cq);
      v4f tp; TILE_MFMA(cur, tp);
      #pragma unroll
      for (int r = 0; r < 4; ++r)
        #pragma unroll
        for (int cc = 0; cc < 3; ++cc)
          racc[t][r][cc] = fmaf(xvS[q * 4 + r][3 * i0 + cc], tp[r], racc[t][r][cc]);
      cur = nxt;
    }
    #pragma unroll
    for (int m = 0; m < 2; ++m)
      #pragma unroll
      for (int r = 0; r < 4; ++r)
        #pragma unroll
        for (int cc = 0; cc < 3; ++cc)
          atomicAdd(&valsS[q * 4 + r][64 + 3 * (m * 16 + cq) + cc], racc[m][r][cc]);
  }

  // ---- w4: 4 tiles/wave. T = 448 + ch*16 + w*4 + t; i=(T-448)>>2, o=(t&3)*16+cq
  {
    const int T0 = 448 + ch * 16 + w * 4;
    const int i0 = (T0 - 448) >> 2;
    float racc[4][4] = {{0.f}};
    BF cur = load_bf(W2fh, W2fl, b2, T0, l, cq);
    #pragma unroll
    for (int t = 0; t < 4; ++t) {
      BF nxt;
      if (t < 3) nxt = load_bf(W2fh, W2fl, b2, T0 + t + 1, l, cq);
      v4f tp; TILE_MFMA(cur, tp);
      #pragma unroll
      for (int r = 0; r < 4; ++r)
        racc[t][r] = fmaf(xvuS[q * 4 + r][i0], tp[r], racc[t][r]);
      cur = nxt;
    }
    #pragma unroll
    for (int m = 0; m < 4; ++m)
      #pragma unroll
      for (int r = 0; r < 4; ++r)
        atomicAdd(&valsS[q * 4 + r][m * 16 + cq], racc[m][r]);
  }
  #undef TILE_MFMA
  __syncthreads();

  // flush: combine sv*y1, one atomicAdd per element (8-way across ch blocks).
  for (int idx = tid; idx < 2560; idx += 256) {
    int n = idx / 160, d = idx - n * 160;
    float v = valsS[n][d];
    if (d >= 64) {
      int dd = d - 64, o = dd / 3, cc = dd - 3 * o;
      v = fmaf(svS[n][o], y1S[n][cc], v);
    }
    atomicAdd(&values[(size_t)(g0 + n) * 160 + d], ALPHAF * v);
  }
}

// ---------------------------------------------------------------------------
// K3 v4: MFMA gate MLP + aggregation per (b,e). grid=2048, block=256.
// (unchanged)
// ---------------------------------------------------------------------------
__global__ void __launch_bounds__(256, 4) k_gate_agg(
    const float* __restrict__ Pa, const float* __restrict__ Pe,
    const float* __restrict__ Pn,
    const unsigned short* __restrict__ W1fh, const unsigned short* __restrict__ W1fl,
    const float* __restrict__ b1, const float* __restrict__ W2v,
    const float* __restrict__ b2s, const float* __restrict__ y1cw,
    const float* __restrict__ values, float* __restrict__ inv_agg) {
  const int bid = blockIdx.x;
  const int b = bid >> 7, e = bid & 127;
  const int tid = threadIdx.x;

  __shared__ float Prow[128];
  __shared__ float gpre[64];
  __shared__ float gateL[64];
  __shared__ float aggL[160];
  __shared__ float normS;

  if (tid < 128) Prow[tid] = Pa[b * 128 + tid] + Pe[e * 128 + tid];
  __syncthreads();

  const int w = tid >> 6, l = tid & 63;
  const int q = l >> 4, cq = l & 15;
  const int node = w * 16 + cq;
  const float* pnrow = Pn + (size_t)(b * 64 + node) * 128;

  v4f acc[8];
  #pragma unroll
  for (int t = 0; t < 8; ++t) acc[t] = (v4f){0.f, 0.f, 0.f, 0.f};

  #pragma unroll
  for (int ks = 0; ks < 4; ++ks) {
    const int k0 = ks * 32 + q * 8;
    float4 p0 = *(const float4*)(pnrow + k0);
    float4 p1 = *(const float4*)(pnrow + k0 + 4);
    float4 r0 = *(const float4*)(&Prow[k0]);
    float4 r1 = *(const float4*)(&Prow[k0 + 4]);
    float xv[8] = {p0.x + r0.x, p0.y + r0.y, p0.z + r0.z, p0.w + r0.w,
                   p1.x + r1.x, p1.y + r1.y, p1.z + r1.z, p1.w + r1.w};
    v8s avh, avl;
    #pragma unroll
    for (int j = 0; j < 8; ++j) {
      float x = silu_f(xv[j]);
      unsigned short h = f2bf(x);
      avh[j] = (short)h;
      avl[j] = (short)f2bf(x - bf2f(h));
    }
    #pragma unroll
    for (int t = 0; t < 8; ++t) {
      const size_t fb = (size_t)((ks * 8 + t) * 64 + l) * 8;
      v8s bh = *(const v8s*)&W1fh[fb];
      v8s bl = *(const v8s*)&W1fl[fb];
      acc[t] = __builtin_amdgcn_mfma_f32_16x16x32_bf16(avh, bh, acc[t], 0, 0, 0);
      acc[t] = __builtin_amdgcn_mfma_f32_16x16x32_bf16(avl, bh, acc[t], 0, 0, 0);
      acc[t] = __builtin_amdgcn_mfma_f32_16x16x32_bf16(avh, bl, acc[t], 0, 0, 0);
    }
  }

  float part0 = 0.f, part1 = 0.f, part2 = 0.f, part3 = 0.f;
  #pragma unroll
  for (int t = 0; t < 8; ++t) {
    float bb = b1[t * 16 + cq];
    float wg = W2v[t * 16 + cq];
    part0 = fmaf(silu_f(acc[t][0] + bb), wg, part0);
    part1 = fmaf(silu_f(acc[t][1] + bb), wg, part1);
    part2 = fmaf(silu_f(acc[t][2] + bb), wg, part2);
    part3 = fmaf(silu_f(acc[t][3] + bb), wg, part3);
  }
  #pragma unroll
  for (int off = 1; off < 16; off <<= 1) {
    part0 += __shfl_xor(part0, off);
    part1 += __shfl_xor(part1, off);
    part2 += __shfl_xor(part2, off);
    part3 += __shfl_xor(part3, off);
  }
  if (cq == 0) {
    gpre[w * 16 + q * 4 + 0] = part0;
    gpre[w * 16 + q * 4 + 1] = part1;
    gpre[w * 16 + q * 4 + 2] = part2;
    gpre[w * 16 + q * 4 + 3] = part3;
  }
  __syncthreads();

  if (tid < 64) {
    float gv = sigmoid_f(gpre[tid] + b2s[0]);
    gv *= y1cw[(b * 64 + tid) * 4 + 3];
    gateL[tid] = gv;
    float t2 = gv;
    #pragma unroll
    for (int off = 32; off > 0; off >>= 1) t2 += __shfl_down(t2, off);
    if (tid == 0) normS = fmaxf(t2, 1e-8f);
  }
  __syncthreads();

  if (tid < 160) {
    float a = 0.0f;
    const float* vp = values + (size_t)b * 64 * 160 + tid;
    #pragma unroll 4
    for (int n = 0; n < 64; ++n) a = fmaf(gateL[n], vp[n * 160], a);
    aggL[tid] = a / normS;
  }
  __syncthreads();
  if (tid < 96) {
    float rv;
    if (tid < 64) {
      rv = aggL[tid];
    } else {
      int o = tid - 64;
      float a0 = aggL[64 + o * 3 + 0];
      float a1 = aggL[64 + o * 3 + 1];
      float a2 = aggL[64 + o * 3 + 2];
      rv = sqrtf((a0 * a0 + a1 * a1 + a2 * a2) * (1.0f / 3.0f) + 1e-8f);
    }
    inv_agg[bid * 96 + tid] = rv;
  }
}

// ---------------------------------------------------------------------------
// K4: MLP layer Y = act(X@W + b). 32-row tiles -> 64 blocks. K in {96,128}.
// ---------------------------------------------------------------------------
__global__ void __launch_bounds__(256) k_mlp(
    const float* __restrict__ X, const float* __restrict__ W,
    const float* __restrict__ bias, float* __restrict__ Y,
    int K, int act) {
  const int r0 = blockIdx.x * 32;
  const int tid = threadIdx.x;

  __shared__ float A[32][129];

  for (int idx = tid; idx < 32 * K; idx += 256) {
    int n = idx / K, k = idx - n * K;
    A[n][k] = X[(size_t)(r0 + n) * K + k];
  }
  __syncthreads();

  const int rowg = tid >> 4, colg = tid & 15;
  const int r2 = rowg * 2, c8 = colg * 8;

  float acc[2][8];
  #pragma unroll
  for (int i = 0; i < 2; ++i)
    #pragma unroll
    for (int jj = 0; jj < 8; ++jj) acc[i][jj] = 0.0f;

  const float* wptr = W + c8;
  #pragma unroll 4
  for (int k = 0; k < K; ++k) {
    float4 w0 = *(const float4*)(wptr + k * 128);
    float4 w1v = *(const float4*)(wptr + k * 128 + 4);
    float av0 = A[r2 + 0][k];
    float av1 = A[r2 + 1][k];
    float wv[8] = {w0.x, w0.y, w0.z, w0.w, w1v.x, w1v.y, w1v.z, w1v.w};
    #pragma unroll
    for (int jj = 0; jj < 8; ++jj) {
      acc[0][jj] = fmaf(av0, wv[jj], acc[0][jj]);
      acc[1][jj] = fmaf(av1, wv[jj], acc[1][jj]);
    }
  }

  #pragma unroll
  for (int jj = 0; jj < 8; ++jj) {
    float bb = bias[c8 + jj];
    #pragma unroll
    for (int i = 0; i < 2; ++i) {
      float v = acc[i][jj] + bb;
      if (act) v = silu_f(v);
      Y[(size_t)(r0 + r2 + i) * 128 + c8 + jj] = v;
    }
  }
}

// ---------------------------------------------------------------------------
extern "C" void kernel_launch(void* const* d_in, const int* in_sizes, int n_in,
                              void* d_out, int out_size, void* d_ws, size_t ws_size,
                              hipStream_t stream) {
  const float* hf    = (const float*)d_in[0];
  const int*   z     = (const int*)  d_in[1];
  const float* pos   = (const float*)d_in[2];
  const float* e_feat= (const float*)d_in[4];
  const float* z_emb = (const float*)d_in[5];
  const float* vwW0  = (const float*)d_in[6];
  const float* vwb0  = (const float*)d_in[7];
  const float* vwW1  = (const float*)d_in[8];
  const float* vwb1  = (const float*)d_in[9];
  const float* vwW2  = (const float*)d_in[10];
  const float* vwb2  = (const float*)d_in[11];
  const float* scW0  = (const float*)d_in[12];
  const float* scb0  = (const float*)d_in[13];
  const float* scW1  = (const float*)d_in[14];
  const float* scb1  = (const float*)d_in[15];
  const float* scW2  = (const float*)d_in[16];
  const float* scb2  = (const float*)d_in[17];
  const float* oW0   = (const float*)d_in[18];
  const float* ob0   = (const float*)d_in[19];
  const float* oW1   = (const float*)d_in[20];
  const float* ob1   = (const float*)d_in[21];
  const float* oW2   = (const float*)d_in[22];
  const float* ob2   = (const float*)d_in[23];
  float* out = (float*)d_out;

  float* ws = (float*)d_ws;
  unsigned short* W2fh = (unsigned short*)(ws);            // 589824 fl
  unsigned short* W2fl = (unsigned short*)(ws + 589824);   // 589824 fl
  unsigned short* hTh  = (unsigned short*)(ws + 1179648);  // 65536 fl
  unsigned short* hTl  = (unsigned short*)(ws + 1245184);  // 65536 fl
  float* Pn     = ws + 1310720;   // 131072
  float* Pa     = Pn + 131072;    // 2048
  float* Pe     = Pa + 2048;      // 16384
  float* xvu    = Pe + 16384;     // 32768
  float* y1cw   = xvu + 32768;    // 4096
  float* values = y1cw + 4096;    // 163840
  float* invagg = values + 163840;// 196608
  unsigned short* W1fh = (unsigned short*)(invagg + 196608);  // 8192 fl
  unsigned short* W1fl = (unsigned short*)(invagg + 196608 + 8192);
  // H1/H2 alias the W2f region (dead after k_tp)
  float* H1     = ws;             // 262144
  float* H2     = ws + 262144;    // 262144

  hipMemsetAsync(values, 0, 163840 * sizeof(float), stream);

  k_castw2<<<576, 256, 0, stream>>>(vwW2, W2fh, W2fl);
  k_castw1<<<8, 256, 0, stream>>>(scW1, W1fh, W1fl);
  k_prep<<<256, 128, 0, stream>>>(hf, z, pos, z_emb, vwW0, vwb0, vwW1, vwb1,
                                  scW0, hTh, hTl, Pn, Pa, xvu, y1cw);
  k_pe<<<128, 128, 0, stream>>>(e_feat, scW0, scb0, Pe);
  k_tp<<<dim3(64, 8), 256, 0, stream>>>(hTh, hTl, W2fh, W2fl, vwb2, hf, xvu,
                                        y1cw, values);
  k_gate_agg<<<2048, 256, 0, stream>>>(Pa, Pe, Pn, W1fh, W1fl, scb1, scW2, scb2,
                                       y1cw, values, invagg);
  k_mlp<<<64, 256, 0, stream>>>(invagg, oW0, ob0, H1, 96, 1);
  k_mlp<<<64, 256, 0, stream>>>(H1, oW1, ob1, H2, 128, 1);
  k_mlp<<<64, 256, 0, stream>>>(H2, oW2, ob2, out, 128, 0);
}

// Round 10
// 333.952 us; speedup vs baseline: 1.1820x; 1.0048x over previous
//
#include <hip/hip_runtime.h>
#include <hip/hip_bf16.h>
#include <math.h>

// Sizes: B=16, N=64, nE=128, H=128, LAT=128, NS=64, NV=32, INV=96, D_NODE=160
#define SQRT3F 1.7320508075688772f
#define ALPHAF 0.10206207261596577f  // 1/sqrt(96)
#define PIF 3.14159265358979323846f

typedef short v8s __attribute__((ext_vector_type(8)));
typedef float v4f __attribute__((ext_vector_type(4)));

__device__ __forceinline__ float silu_f(float x) {
  return x / (1.0f + __expf(-x));
}
__device__ __forceinline__ float sigmoid_f(float x) {
  return 1.0f / (1.0f + __expf(-x));
}
__device__ __forceinline__ unsigned short f2bf(float f) {
  unsigned int u = __float_as_uint(f);
  unsigned int r = (u + 0x7fffu + ((u >> 16) & 1u)) >> 16;
  return (unsigned short)r;
}
__device__ __forceinline__ float bf2f(unsigned short h) {
  return __uint_as_float(((unsigned int)h) << 16);
}

// ---------------------------------------------------------------------------
// K-1 v2: cast W2 (128 x 9216 fp32) into MFMA B-FRAGMENT order, bf16 hi/lo.
// ---------------------------------------------------------------------------
__global__ void __launch_bounds__(256) k_castw2(
    const float* __restrict__ W2, unsigned short* __restrict__ W2fh,
    unsigned short* __restrict__ W2fl) {
  const int T = blockIdx.x;           // column tile of 16
  const int tid = threadIdx.x;
  __shared__ float Tl[128][17];

  for (int idx = tid; idx < 2048; idx += 256) {
    int k = idx >> 4, cc = idx & 15;
    Tl[k][cc] = W2[(size_t)k * 9216 + T * 16 + cc];
  }
  __syncthreads();

  const int ks = tid >> 6, lane = tid & 63;
  const int q = lane >> 4, cq = lane & 15;
  const int k0 = ks * 32 + q * 8;
  unsigned short hv[8], lv[8];
  #pragma unroll
  for (int j = 0; j < 8; ++j) {
    float wv = Tl[k0 + j][cq];
    unsigned short h = f2bf(wv);
    hv[j] = h;
    lv[j] = f2bf(wv - bf2f(h));
  }
  size_t base = ((size_t)(T * 4 + ks) * 64 + lane) * 8;
  *(uint4*)&W2fh[base] = *(uint4*)hv;
  *(uint4*)&W2fl[base] = *(uint4*)lv;
}

// ---------------------------------------------------------------------------
// K-2: pack sc_W1 (128x128) into MFMA B-fragment order, bf16 hi/lo.
// ---------------------------------------------------------------------------
__global__ void __launch_bounds__(256) k_castw1(
    const float* __restrict__ W1, unsigned short* __restrict__ W1fh,
    unsigned short* __restrict__ W1fl) {
  const int s = blockIdx.x * 256 + threadIdx.x;   // 0..2047
  const int lane = s & 63;
  const int t = (s >> 6) & 7;
  const int ks = s >> 9;
  const int kbase = ks * 32 + (lane >> 4) * 8;
  const int n = t * 16 + (lane & 15);
  unsigned short hv[8], lv[8];
  #pragma unroll
  for (int j = 0; j < 8; ++j) {
    float w = W1[(size_t)(kbase + j) * 128 + n];
    unsigned short h = f2bf(w);
    hv[j] = h;
    lv[j] = f2bf(w - bf2f(h));
  }
  *(uint4*)&W1fh[(size_t)s * 8] = *(uint4*)hv;
  *(uint4*)&W1fl[(size_t)s * 8] = *(uint4*)lv;
}

// ---------------------------------------------------------------------------
// K0: per-node prep, 4 nodes per block. grid=256, block=128.
// ---------------------------------------------------------------------------
__global__ void k_prep(const float* __restrict__ hf, const int* __restrict__ z,
                       const float* __restrict__ pos, const float* __restrict__ z_emb,
                       const float* __restrict__ vwW0, const float* __restrict__ vwb0,
                       const float* __restrict__ vwW1, const float* __restrict__ vwb1,
                       const float* __restrict__ scW0,
                       unsigned short* __restrict__ hTh, unsigned short* __restrict__ hTl,
                       float* __restrict__ Pn, float* __restrict__ Pa,
                       float* __restrict__ xvu, float* __restrict__ y1cw) {
  const int g0 = blockIdx.x * 4;
  const int b = g0 >> 6;
  const int t = threadIdx.x;

  __shared__ float vin[4][64];
  __shared__ float invn[4][96];
  __shared__ float h0[4][128];
  __shared__ float uS[4][3];
  __shared__ float rS[4];

  if (t < 4) {
    const int g = g0 + t;
    float px = pos[g * 3 + 0] - pos[(b * 64) * 3 + 0];
    float py = pos[g * 3 + 1] - pos[(b * 64) * 3 + 1];
    float pz = pos[g * 3 + 2] - pos[(b * 64) * 3 + 2];
    float r = sqrtf(px * px + py * py + pz * pz + 1e-12f);
    float rm = fmaxf(r, 1e-8f);
    uS[t][0] = px / rm; uS[t][1] = py / rm; uS[t][2] = pz / rm;
    rS[t] = r;
  }
  __syncthreads();

  if (t < 32) {
    const float delta = 6.0f / 31.0f;
    const float gamma = 1.0f / (delta * delta + 1e-12f);
    #pragma unroll
    for (int nn = 0; nn < 4; ++nn) {
      int zi = z[g0 + nn];
      vin[nn][t] = z_emb[zi * 32 + t];
      float rc = fminf(rS[nn], 6.0f);
      float d = rc - (float)t * delta;
      vin[nn][32 + t] = __expf(-gamma * d * d);
      float a = hf[(g0 + nn) * 160 + 64 + t * 3 + 0] * uS[nn][0]
              + hf[(g0 + nn) * 160 + 64 + t * 3 + 1] * uS[nn][1]
              + hf[(g0 + nn) * 160 + 64 + t * 3 + 2] * uS[nn][2];
      xvu[(g0 + nn) * 32 + t] = a;
    }
  }
  if (t < 96) {
    #pragma unroll
    for (int nn = 0; nn < 4; ++nn) {
      const int g = g0 + nn;
      if (t < 64) {
        invn[nn][t] = hf[g * 160 + t];
      } else {
        int o = t - 64;
        float v0 = hf[g * 160 + 64 + o * 3 + 0];
        float v1 = hf[g * 160 + 64 + o * 3 + 1];
        float v2 = hf[g * 160 + 64 + o * 3 + 2];
        invn[nn][t] = sqrtf((v0 * v0 + v1 * v1 + v2 * v2) * (1.0f / 3.0f) + 1e-8f);
      }
    }
  }
  if (t < 4) {
    const int n = (g0 + t) & 63;
    float r = rS[t];
    float cw = 0.0f;
    if (r <= 6.0f && n != 0) cw = 0.5f * (cosf(PIF * r * (1.0f / 6.0f)) + 1.0f);
    y1cw[(g0 + t) * 4 + 0] = SQRT3F * uS[t][0];
    y1cw[(g0 + t) * 4 + 1] = SQRT3F * uS[t][1];
    y1cw[(g0 + t) * 4 + 2] = SQRT3F * uS[t][2];
    y1cw[(g0 + t) * 4 + 3] = cw;
  }
  __syncthreads();

  {
    float a0 = vwb0[t], a1 = a0, a2 = a0, a3 = a0;
    #pragma unroll 8
    for (int k = 0; k < 64; ++k) {
      float w = vwW0[k * 128 + t];
      a0 = fmaf(vin[0][k], w, a0);
      a1 = fmaf(vin[1][k], w, a1);
      a2 = fmaf(vin[2][k], w, a2);
      a3 = fmaf(vin[3][k], w, a3);
    }
    h0[0][t] = silu_f(a0); h0[1][t] = silu_f(a1);
    h0[2][t] = silu_f(a2); h0[3][t] = silu_f(a3);
  }
  __syncthreads();
  {
    float a0 = vwb1[t], a1 = a0, a2 = a0, a3 = a0;
    #pragma unroll 8
    for (int k = 0; k < 128; ++k) {
      float w = vwW1[k * 128 + t];
      a0 = fmaf(h0[0][k], w, a0);
      a1 = fmaf(h0[1][k], w, a1);
      a2 = fmaf(h0[2][k], w, a2);
      a3 = fmaf(h0[3][k], w, a3);
    }
    float hv[4] = {silu_f(a0), silu_f(a1), silu_f(a2), silu_f(a3)};
    #pragma unroll
    for (int nn = 0; nn < 4; ++nn) {
      unsigned short hh = f2bf(hv[nn]);
      hTh[(size_t)(g0 + nn) * 128 + t] = hh;
      hTl[(size_t)(g0 + nn) * 128 + t] = f2bf(hv[nn] - bf2f(hh));
    }
  }
  {
    float p0 = 0.f, p1 = 0.f, p2 = 0.f, p3 = 0.f;
    #pragma unroll 8
    for (int k = 0; k < 96; ++k) {
      float w = scW0[(96 + k) * 128 + t];
      p0 = fmaf(invn[0][k], w, p0);
      p1 = fmaf(invn[1][k], w, p1);
      p2 = fmaf(invn[2][k], w, p2);
      p3 = fmaf(invn[3][k], w, p3);
    }
    #pragma unroll 8
    for (int k = 0; k < 64; ++k) {
      float w = scW0[(192 + k) * 128 + t];
      p0 = fmaf(vin[0][k], w, p0);
      p1 = fmaf(vin[1][k], w, p1);
      p2 = fmaf(vin[2][k], w, p2);
      p3 = fmaf(vin[3][k], w, p3);
    }
    Pn[(g0 + 0) * 128 + t] = p0;
    Pn[(g0 + 1) * 128 + t] = p1;
    Pn[(g0 + 2) * 128 + t] = p2;
    Pn[(g0 + 3) * 128 + t] = p3;
  }
  if ((g0 & 63) == 0) {
    float p = 0.0f;
    #pragma unroll 8
    for (int k = 0; k < 96; ++k) p = fmaf(invn[0][k], scW0[k * 128 + t], p);
    Pa[b * 128 + t] = p;
  }
}

// ---------------------------------------------------------------------------
// KPe: Pe[e][t] = sc_b0[t] + e_feat[e]@We. grid=128, block=128.
// ---------------------------------------------------------------------------
__global__ void k_pe(const float* __restrict__ e_feat, const float* __restrict__ scW0,
                     const float* __restrict__ scb0, float* __restrict__ Pe) {
  const int e = blockIdx.x;
  const int t = threadIdx.x;
  float a = scb0[t];
  #pragma unroll
  for (int k = 0; k < 16; ++k) a = fmaf(e_feat[e * 16 + k], scW0[(256 + k) * 128 + t], a);
  Pe[e * 128 + t] = a;
}

// ---------------------------------------------------------------------------
// K2 v10: MFMA GEMM + register contraction.
// 1D grid 512: ch = bid & 7, tile = bid >> 3. Under round-robin block->XCD
// dispatch this pins each ch-slice (590KB of W2f) to one XCD's L2 — R9's
// 19.3MB FETCH came from every XCD streaming all 4.7MB through 4MB L2.
// Also: 12-MFMA tile chain split into 3 independent 4-chains (hh/lh/hl).
// ---------------------------------------------------------------------------
struct BF {
  v8s h0, h1, h2, h3, l0, l1, l2, l3;
  float bias;
};

__device__ __forceinline__ BF load_bf(const unsigned short* __restrict__ W2fh,
                                      const unsigned short* __restrict__ W2fl,
                                      const float* __restrict__ b2,
                                      int T, int l, int cq) {
  BF f;
  const size_t base = (size_t)T * 2048 + (size_t)l * 8;
  f.h0 = *(const v8s*)(W2fh + base);
  f.h1 = *(const v8s*)(W2fh + base + 512);
  f.h2 = *(const v8s*)(W2fh + base + 1024);
  f.h3 = *(const v8s*)(W2fh + base + 1536);
  f.l0 = *(const v8s*)(W2fl + base);
  f.l1 = *(const v8s*)(W2fl + base + 512);
  f.l2 = *(const v8s*)(W2fl + base + 1024);
  f.l3 = *(const v8s*)(W2fl + base + 1536);
  f.bias = b2[T * 16 + cq];
  return f;
}

__global__ void __launch_bounds__(256) k_tp(
    const unsigned short* __restrict__ hTh, const unsigned short* __restrict__ hTl,
    const unsigned short* __restrict__ W2fh, const unsigned short* __restrict__ W2fl,
    const float* __restrict__ b2, const float* __restrict__ hf,
    const float* __restrict__ xvu, const float* __restrict__ y1cw,
    float* __restrict__ values) {
  const int bid = blockIdx.x;
  const int ch = bid & 7;             // XCD-aligned col split
  const int g0 = (bid >> 3) * 16;     // node tile
  const int tid = threadIdx.x;
  const int w = tid >> 6, l = tid & 63;
  const int q = l >> 4, cq = l & 15;

  __shared__ float xsS[16][64];
  __shared__ float xvS[16][96];
  __shared__ float xvuS[16][32];
  __shared__ float y1S[16][4];
  __shared__ float valsS[16][160];
  __shared__ float svS[16][32];

  for (int idx = tid; idx < 16 * 64; idx += 256) {
    int n = idx >> 6, i = idx & 63;
    xsS[n][i] = hf[(size_t)(g0 + n) * 160 + i];
  }
  for (int idx = tid; idx < 16 * 96; idx += 256) {
    int n = idx / 96, k = idx - n * 96;
    xvS[n][k] = hf[(size_t)(g0 + n) * 160 + 64 + k];
  }
  for (int idx = tid; idx < 16 * 32; idx += 256) {
    int n = idx >> 5, i = idx & 31;
    xvuS[n][i] = xvu[(size_t)(g0 + n) * 32 + i];
  }
  if (tid < 64) ((float*)y1S)[tid] = y1cw[(size_t)g0 * 4 + tid];
  for (int idx = tid; idx < 16 * 160; idx += 256) ((float*)valsS)[idx] = 0.f;
  for (int idx = tid; idx < 16 * 32; idx += 256) ((float*)svS)[idx] = 0.f;

  v8s ah0 = *(const v8s*)&hTh[(size_t)(g0 + cq) * 128 + 0 * 32 + q * 8];
  v8s ah1 = *(const v8s*)&hTh[(size_t)(g0 + cq) * 128 + 1 * 32 + q * 8];
  v8s ah2 = *(const v8s*)&hTh[(size_t)(g0 + cq) * 128 + 2 * 32 + q * 8];
  v8s ah3 = *(const v8s*)&hTh[(size_t)(g0 + cq) * 128 + 3 * 32 + q * 8];
  v8s al0 = *(const v8s*)&hTl[(size_t)(g0 + cq) * 128 + 0 * 32 + q * 8];
  v8s al1 = *(const v8s*)&hTl[(size_t)(g0 + cq) * 128 + 1 * 32 + q * 8];
  v8s al2 = *(const v8s*)&hTl[(size_t)(g0 + cq) * 128 + 2 * 32 + q * 8];
  v8s al3 = *(const v8s*)&hTl[(size_t)(g0 + cq) * 128 + 3 * 32 + q * 8];
  __syncthreads();

  // 3 independent 4-chains (hh / lh / hl), summed at the end.
  #define TILE_MFMA(f, outp)                                                   \
    {                                                                          \
      v4f a0_ = (v4f){0.f, 0.f, 0.f, 0.f};                                     \
      v4f a1_ = (v4f){0.f, 0.f, 0.f, 0.f};                                     \
      v4f a2_ = (v4f){0.f, 0.f, 0.f, 0.f};                                     \
      a0_ = __builtin_amdgcn_mfma_f32_16x16x32_bf16(ah0, (f).h0, a0_, 0, 0, 0);\
      a1_ = __builtin_amdgcn_mfma_f32_16x16x32_bf16(al0, (f).h0, a1_, 0, 0, 0);\
      a2_ = __builtin_amdgcn_mfma_f32_16x16x32_bf16(ah0, (f).l0, a2_, 0, 0, 0);\
      a0_ = __builtin_amdgcn_mfma_f32_16x16x32_bf16(ah1, (f).h1, a0_, 0, 0, 0);\
      a1_ = __builtin_amdgcn_mfma_f32_16x16x32_bf16(al1, (f).h1, a1_, 0, 0, 0);\
      a2_ = __builtin_amdgcn_mfma_f32_16x16x32_bf16(ah1, (f).l1, a2_, 0, 0, 0);\
      a0_ = __builtin_amdgcn_mfma_f32_16x16x32_bf16(ah2, (f).h2, a0_, 0, 0, 0);\
      a1_ = __builtin_amdgcn_mfma_f32_16x16x32_bf16(al2, (f).h2, a1_, 0, 0, 0);\
      a2_ = __builtin_amdgcn_mfma_f32_16x16x32_bf16(ah2, (f).l2, a2_, 0, 0, 0);\
      a0_ = __builtin_amdgcn_mfma_f32_16x16x32_bf16(ah3, (f).h3, a0_, 0, 0, 0);\
      a1_ = __builtin_amdgcn_mfma_f32_16x16x32_bf16(al3, (f).h3, a1_, 0, 0, 0);\
      a2_ = __builtin_amdgcn_mfma_f32_16x16x32_bf16(ah3, (f).l3, a2_, 0, 0, 0);\
      a0_ += a1_; a0_ += a2_;                                                  \
      a0_[0] += (f).bias; a0_[1] += (f).bias;                                  \
      a0_[2] += (f).bias; a0_[3] += (f).bias;                                  \
      outp = a0_;                                                              \
    }

  // ---- w1: 8 tiles/wave. T = ch*32 + w*8 + t; i=T>>2, o=(t&3)*16+cq ----
  {
    const int T0 = ch * 32 + w * 8;
    const int i0 = T0 >> 2;
    float racc[4][4] = {{0.f}};
    BF cur = load_bf(W2fh, W2fl, b2, T0, l, cq);
    #pragma unroll
    for (int t = 0; t < 8; ++t) {
      BF nxt;
      if (t < 7) nxt = load_bf(W2fh, W2fl, b2, T0 + t + 1, l, cq);
      v4f tp; TILE_MFMA(cur, tp);
      const int ii = t >> 2, m = t & 3;
      #pragma unroll
      for (int r = 0; r < 4; ++r)
        racc[m][r] = fmaf(xsS[q * 4 + r][i0 + ii], tp[r], racc[m][r]);
      cur = nxt;
    }
    #pragma unroll
    for (int m = 0; m < 4; ++m)
      #pragma unroll
      for (int r = 0; r < 4; ++r)
        atomicAdd(&valsS[q * 4 + r][m * 16 + cq], racc[m][r]);
  }

  // ---- w2: 4 tiles/wave. T = 256 + ch*16 + w*4 + t ----
  {
    const int T0 = 256 + ch * 16 + w * 4;
    const int i0 = (T0 - 256) >> 1;
    float racc[2][4] = {{0.f}};
    BF cur = load_bf(W2fh, W2fl, b2, T0, l, cq);
    #pragma unroll
    for (int t = 0; t < 4; ++t) {
      BF nxt;
      if (t < 3) nxt = load_bf(W2fh, W2fl, b2, T0 + t + 1, l, cq);
      v4f tp; TILE_MFMA(cur, tp);
      const int ii = t >> 1, m = t & 1;
      #pragma unroll
      for (int r = 0; r < 4; ++r)
        racc[m][r] = fmaf(xsS[q * 4 + r][i0 + ii], tp[r], racc[m][r]);
      cur = nxt;
    }
    #pragma unroll
    for (int m = 0; m < 2; ++m)
      #pragma unroll
      for (int r = 0; r < 4; ++r)
        atomicAdd(&svS[q * 4 + r][m * 16 + cq], racc[m][r]);
  }

  // ---- w3: 2 tiles/wave. T = 384 + ch*8 + w*2 + t ----
  {
    const int T0 = 384 + ch * 8 + w * 2;
    const int i0 = (T0 - 384) >> 1;
    float racc[2][4][3] = {{{0.f}}};
    BF cur = load_bf(W2fh, W2fl, b2, T0, l, cq);
    #pragma unroll
    for (int t = 0; t < 2; ++t) {
      BF nxt;
      if (t < 1) nxt = load_bf(W2fh, W2fl, b2, T0 + 1, l, cq);
      v4f tp; TILE_MFMA(cur, tp);
      #pragma unroll
      for (int r = 0; r < 4; ++r)
        #pragma unroll
        for (int cc = 0; cc < 3; ++cc)
          racc[t][r][cc] = fmaf(xvS[q * 4 + r][3 * i0 + cc], tp[r], racc[t][r][cc]);
      cur = nxt;
    }
    #pragma unroll
    for (int m = 0; m < 2; ++m)
      #pragma unroll
      for (int r = 0; r < 4; ++r)
        #pragma unroll
        for (int cc = 0; cc < 3; ++cc)
          atomicAdd(&valsS[q * 4 + r][64 + 3 * (m * 16 + cq) + cc], racc[m][r][cc]);
  }

  // ---- w4: 4 tiles/wave. T = 448 + ch*16 + w*4 + t ----
  {
    const int T0 = 448 + ch * 16 + w * 4;
    const int i0 = (T0 - 448) >> 2;
    float racc[4][4] = {{0.f}};
    BF cur = load_bf(W2fh, W2fl, b2, T0, l, cq);
    #pragma unroll
    for (int t = 0; t < 4; ++t) {
      BF nxt;
      if (t < 3) nxt = load_bf(W2fh, W2fl, b2, T0 + t + 1, l, cq);
      v4f tp; TILE_MFMA(cur, tp);
      #pragma unroll
      for (int r = 0; r < 4; ++r)
        racc[t][r] = fmaf(xvuS[q * 4 + r][i0], tp[r], racc[t][r]);
      cur = nxt;
    }
    #pragma unroll
    for (int m = 0; m < 4; ++m)
      #pragma unroll
      for (int r = 0; r < 4; ++r)
        atomicAdd(&valsS[q * 4 + r][m * 16 + cq], racc[m][r]);
  }
  #undef TILE_MFMA
  __syncthreads();

  for (int idx = tid; idx < 2560; idx += 256) {
    int n = idx / 160, d = idx - n * 160;
    float v = valsS[n][d];
    if (d >= 64) {
      int dd = d - 64, o = dd / 3, cc = dd - 3 * o;
      v = fmaf(svS[n][o], y1S[n][cc], v);
    }
    atomicAdd(&values[(size_t)(g0 + n) * 160 + d], ALPHAF * v);
  }
}

// ---------------------------------------------------------------------------
// K3 v4: MFMA gate MLP + aggregation per (b,e). grid=2048, block=256.
// ---------------------------------------------------------------------------
__global__ void __launch_bounds__(256, 4) k_gate_agg(
    const float* __restrict__ Pa, const float* __restrict__ Pe,
    const float* __restrict__ Pn,
    const unsigned short* __restrict__ W1fh, const unsigned short* __restrict__ W1fl,
    const float* __restrict__ b1, const float* __restrict__ W2v,
    const float* __restrict__ b2s, const float* __restrict__ y1cw,
    const float* __restrict__ values, float* __restrict__ inv_agg) {
  const int bid = blockIdx.x;
  const int b = bid >> 7, e = bid & 127;
  const int tid = threadIdx.x;

  __shared__ float Prow[128];
  __shared__ float gpre[64];
  __shared__ float gateL[64];
  __shared__ float aggL[160];
  __shared__ float normS;

  if (tid < 128) Prow[tid] = Pa[b * 128 + tid] + Pe[e * 128 + tid];
  __syncthreads();

  const int w = tid >> 6, l = tid & 63;
  const int q = l >> 4, cq = l & 15;
  const int node = w * 16 + cq;
  const float* pnrow = Pn + (size_t)(b * 64 + node) * 128;

  v4f acc[8];
  #pragma unroll
  for (int t = 0; t < 8; ++t) acc[t] = (v4f){0.f, 0.f, 0.f, 0.f};

  #pragma unroll
  for (int ks = 0; ks < 4; ++ks) {
    const int k0 = ks * 32 + q * 8;
    float4 p0 = *(const float4*)(pnrow + k0);
    float4 p1 = *(const float4*)(pnrow + k0 + 4);
    float4 r0 = *(const float4*)(&Prow[k0]);
    float4 r1 = *(const float4*)(&Prow[k0 + 4]);
    float xv[8] = {p0.x + r0.x, p0.y + r0.y, p0.z + r0.z, p0.w + r0.w,
                   p1.x + r1.x, p1.y + r1.y, p1.z + r1.z, p1.w + r1.w};
    v8s avh, avl;
    #pragma unroll
    for (int j = 0; j < 8; ++j) {
      float x = silu_f(xv[j]);
      unsigned short h = f2bf(x);
      avh[j] = (short)h;
      avl[j] = (short)f2bf(x - bf2f(h));
    }
    #pragma unroll
    for (int t = 0; t < 8; ++t) {
      const size_t fb = (size_t)((ks * 8 + t) * 64 + l) * 8;
      v8s bh = *(const v8s*)&W1fh[fb];
      v8s bl = *(const v8s*)&W1fl[fb];
      acc[t] = __builtin_amdgcn_mfma_f32_16x16x32_bf16(avh, bh, acc[t], 0, 0, 0);
      acc[t] = __builtin_amdgcn_mfma_f32_16x16x32_bf16(avl, bh, acc[t], 0, 0, 0);
      acc[t] = __builtin_amdgcn_mfma_f32_16x16x32_bf16(avh, bl, acc[t], 0, 0, 0);
    }
  }

  float part0 = 0.f, part1 = 0.f, part2 = 0.f, part3 = 0.f;
  #pragma unroll
  for (int t = 0; t < 8; ++t) {
    float bb = b1[t * 16 + cq];
    float wg = W2v[t * 16 + cq];
    part0 = fmaf(silu_f(acc[t][0] + bb), wg, part0);
    part1 = fmaf(silu_f(acc[t][1] + bb), wg, part1);
    part2 = fmaf(silu_f(acc[t][2] + bb), wg, part2);
    part3 = fmaf(silu_f(acc[t][3] + bb), wg, part3);
  }
  #pragma unroll
  for (int off = 1; off < 16; off <<= 1) {
    part0 += __shfl_xor(part0, off);
    part1 += __shfl_xor(part1, off);
    part2 += __shfl_xor(part2, off);
    part3 += __shfl_xor(part3, off);
  }
  if (cq == 0) {
    gpre[w * 16 + q * 4 + 0] = part0;
    gpre[w * 16 + q * 4 + 1] = part1;
    gpre[w * 16 + q * 4 + 2] = part2;
    gpre[w * 16 + q * 4 + 3] = part3;
  }
  __syncthreads();

  if (tid < 64) {
    float gv = sigmoid_f(gpre[tid] + b2s[0]);
    gv *= y1cw[(b * 64 + tid) * 4 + 3];
    gateL[tid] = gv;
    float t2 = gv;
    #pragma unroll
    for (int off = 32; off > 0; off >>= 1) t2 += __shfl_down(t2, off);
    if (tid == 0) normS = fmaxf(t2, 1e-8f);
  }
  __syncthreads();

  if (tid < 160) {
    float a = 0.0f;
    const float* vp = values + (size_t)b * 64 * 160 + tid;
    #pragma unroll 4
    for (int n = 0; n < 64; ++n) a = fmaf(gateL[n], vp[n * 160], a);
    aggL[tid] = a / normS;
  }
  __syncthreads();
  if (tid < 96) {
    float rv;
    if (tid < 64) {
      rv = aggL[tid];
    } else {
      int o = tid - 64;
      float a0 = aggL[64 + o * 3 + 0];
      float a1 = aggL[64 + o * 3 + 1];
      float a2 = aggL[64 + o * 3 + 2];
      rv = sqrtf((a0 * a0 + a1 * a1 + a2 * a2) * (1.0f / 3.0f) + 1e-8f);
    }
    inv_agg[bid * 96 + tid] = rv;
  }
}

// ---------------------------------------------------------------------------
// K4: MLP layer Y = act(X@W + b). 32-row tiles -> 64 blocks. K in {96,128}.
// ---------------------------------------------------------------------------
__global__ void __launch_bounds__(256) k_mlp(
    const float* __restrict__ X, const float* __restrict__ W,
    const float* __restrict__ bias, float* __restrict__ Y,
    int K, int act) {
  const int r0 = blockIdx.x * 32;
  const int tid = threadIdx.x;

  __shared__ float A[32][129];

  for (int idx = tid; idx < 32 * K; idx += 256) {
    int n = idx / K, k = idx - n * K;
    A[n][k] = X[(size_t)(r0 + n) * K + k];
  }
  __syncthreads();

  const int rowg = tid >> 4, colg = tid & 15;
  const int r2 = rowg * 2, c8 = colg * 8;

  float acc[2][8];
  #pragma unroll
  for (int i = 0; i < 2; ++i)
    #pragma unroll
    for (int jj = 0; jj < 8; ++jj) acc[i][jj] = 0.0f;

  const float* wptr = W + c8;
  #pragma unroll 4
  for (int k = 0; k < K; ++k) {
    float4 w0 = *(const float4*)(wptr + k * 128);
    float4 w1v = *(const float4*)(wptr + k * 128 + 4);
    float av0 = A[r2 + 0][k];
    float av1 = A[r2 + 1][k];
    float wv[8] = {w0.x, w0.y, w0.z, w0.w, w1v.x, w1v.y, w1v.z, w1v.w};
    #pragma unroll
    for (int jj = 0; jj < 8; ++jj) {
      acc[0][jj] = fmaf(av0, wv[jj], acc[0][jj]);
      acc[1][jj] = fmaf(av1, wv[jj], acc[1][jj]);
    }
  }

  #pragma unroll
  for (int jj = 0; jj < 8; ++jj) {
    float bb = bias[c8 + jj];
    #pragma unroll
    for (int i = 0; i < 2; ++i) {
      float v = acc[i][jj] + bb;
      if (act) v = silu_f(v);
      Y[(size_t)(r0 + r2 + i) * 128 + c8 + jj] = v;
    }
  }
}

// ---------------------------------------------------------------------------
extern "C" void kernel_launch(void* const* d_in, const int* in_sizes, int n_in,
                              void* d_out, int out_size, void* d_ws, size_t ws_size,
                              hipStream_t stream) {
  const float* hf    = (const float*)d_in[0];
  const int*   z     = (const int*)  d_in[1];
  const float* pos   = (const float*)d_in[2];
  const float* e_feat= (const float*)d_in[4];
  const float* z_emb = (const float*)d_in[5];
  const float* vwW0  = (const float*)d_in[6];
  const float* vwb0  = (const float*)d_in[7];
  const float* vwW1  = (const float*)d_in[8];
  const float* vwb1  = (const float*)d_in[9];
  const float* vwW2  = (const float*)d_in[10];
  const float* vwb2  = (const float*)d_in[11];
  const float* scW0  = (const float*)d_in[12];
  const float* scb0  = (const float*)d_in[13];
  const float* scW1  = (const float*)d_in[14];
  const float* scb1  = (const float*)d_in[15];
  const float* scW2  = (const float*)d_in[16];
  const float* scb2  = (const float*)d_in[17];
  const float* oW0   = (const float*)d_in[18];
  const float* ob0   = (const float*)d_in[19];
  const float* oW1   = (const float*)d_in[20];
  const float* ob1   = (const float*)d_in[21];
  const float* oW2   = (const float*)d_in[22];
  const float* ob2   = (const float*)d_in[23];
  float* out = (float*)d_out;

  float* ws = (float*)d_ws;
  unsigned short* W2fh = (unsigned short*)(ws);            // 589824 fl
  unsigned short* W2fl = (unsigned short*)(ws + 589824);   // 589824 fl
  unsigned short* hTh  = (unsigned short*)(ws + 1179648);  // 65536 fl
  unsigned short* hTl  = (unsigned short*)(ws + 1245184);  // 65536 fl
  float* Pn     = ws + 1310720;   // 131072
  float* Pa     = Pn + 131072;    // 2048
  float* Pe     = Pa + 2048;      // 16384
  float* xvu    = Pe + 16384;     // 32768
  float* y1cw   = xvu + 32768;    // 4096
  float* values = y1cw + 4096;    // 163840
  float* invagg = values + 163840;// 196608
  unsigned short* W1fh = (unsigned short*)(invagg + 196608);  // 8192 fl
  unsigned short* W1fl = (unsigned short*)(invagg + 196608 + 8192);
  // H1/H2 alias the W2f region (dead after k_tp)
  float* H1     = ws;             // 262144
  float* H2     = ws + 262144;    // 262144

  hipMemsetAsync(values, 0, 163840 * sizeof(float), stream);

  k_castw2<<<576, 256, 0, stream>>>(vwW2, W2fh, W2fl);
  k_castw1<<<8, 256, 0, stream>>>(scW1, W1fh, W1fl);
  k_prep<<<256, 128, 0, stream>>>(hf, z, pos, z_emb, vwW0, vwb0, vwW1, vwb1,
                                  scW0, hTh, hTl, Pn, Pa, xvu, y1cw);
  k_pe<<<128, 128, 0, stream>>>(e_feat, scW0, scb0, Pe);
  k_tp<<<512, 256, 0, stream>>>(hTh, hTl, W2fh, W2fl, vwb2, hf, xvu,
                                y1cw, values);
  k_gate_agg<<<2048, 256, 0, stream>>>(Pa, Pe, Pn, W1fh, W1fl, scb1, scW2, scb2,
                                       y1cw, values, invagg);
  k_mlp<<<64, 256, 0, stream>>>(invagg, oW0, ob0, H1, 96, 1);
  k_mlp<<<64, 256, 0, stream>>>(H1, oW1, ob1, H2, 128, 1);
  k_mlp<<<64, 256, 0, stream>>>(H2, oW2, ob2, out, 128, 0);
}